// Round 2
// baseline (704.251 us; speedup 1.0000x reference)
//
#include <hip/hip_runtime.h>
#include <stdint.h>

typedef _Float16 f16x8 __attribute__((ext_vector_type(8)));
typedef _Float16 f16x4 __attribute__((ext_vector_type(4)));
typedef float    f32x4 __attribute__((ext_vector_type(4)));

#define NFIELD 64
#define DIM    128
#define BTOT   8192

// ---------------- prep: fp16 conversions + W transpose into workspace ----------------
// Wt[i][d][j] = W[i][j][d] (fp16), Kh = fp16(K_w), Qh = fp16(Q_w)
__global__ void prep_kernel(const float* __restrict__ W,
                            const float* __restrict__ Kw,
                            const float* __restrict__ Qw,
                            _Float16* __restrict__ Wt,
                            _Float16* __restrict__ Kh,
                            _Float16* __restrict__ Qh) {
  const int blk = blockIdx.x, t = threadIdx.x;
  if (blk < NFIELD) {
    const float* Wi = W + (size_t)blk * NFIELD * DIM;
    _Float16* Wo = Wt + (size_t)blk * DIM * NFIELD;
    for (int idx = t; idx < DIM * NFIELD; idx += 256) {
      int d = idx >> 6, j = idx & 63;
      Wo[idx] = (_Float16)Wi[j * DIM + d];
    }
  } else if (blk == NFIELD) {
    for (int idx = t; idx < DIM * DIM; idx += 256) Kh[idx] = (_Float16)Kw[idx];
  } else {
    for (int idx = t; idx < DIM * DIM; idx += 256) Qh[idx] = (_Float16)Qw[idx];
  }
}

// ---------------- kernel 1: Kf = F @ Kw^T as flat [CB*64,128]@[128,128] GEMM ----------
// No LDS, no barriers. Block = 256 thr (4 waves), 128 rows/block (wave owns 32 rows).
// A/B frag: row = lane&15, k = quad*8+j (K-contiguous). C/D: col = lane&15, row = quad*4+reg.
__global__ __launch_bounds__(256, 4)
void kf_kernel(const float* __restrict__ F,
               const _Float16* __restrict__ Kh,
               _Float16* __restrict__ Kf, int c0) {
  const int t = threadIdx.x;
  const int lane = t & 63, wave = t >> 6;
  const int l15 = lane & 15, quad = lane >> 4;
  const int m0 = blockIdx.x * 128 + wave * 32;              // chunk-local row base

  f32x4 acc[2][8];
#pragma unroll
  for (int mi = 0; mi < 2; ++mi)
#pragma unroll
    for (int nt = 0; nt < 8; ++nt) acc[mi][nt] = (f32x4){0.f, 0.f, 0.f, 0.f};

  const size_t gm0 = (size_t)c0 * NFIELD + m0;              // global row base in F
#pragma unroll
  for (int kt = 0; kt < 4; ++kt) {
    f16x8 af[2];
#pragma unroll
    for (int mi = 0; mi < 2; ++mi) {
      const float* fp = F + (gm0 + mi * 16 + l15) * DIM + kt * 32 + quad * 8;
      float4 f0 = *(const float4*)fp;
      float4 f1 = *(const float4*)(fp + 4);
      f16x8 a;
      a[0] = (_Float16)f0.x; a[1] = (_Float16)f0.y; a[2] = (_Float16)f0.z; a[3] = (_Float16)f0.w;
      a[4] = (_Float16)f1.x; a[5] = (_Float16)f1.y; a[6] = (_Float16)f1.z; a[7] = (_Float16)f1.w;
      af[mi] = a;
    }
#pragma unroll
    for (int nt = 0; nt < 8; ++nt) {
      f16x8 bf = *(const f16x8*)(Kh + (nt * 16 + l15) * DIM + kt * 32 + quad * 8);
      acc[0][nt] = __builtin_amdgcn_mfma_f32_16x16x32_f16(af[0], bf, acc[0][nt], 0, 0, 0);
      acc[1][nt] = __builtin_amdgcn_mfma_f32_16x16x32_f16(af[1], bf, acc[1][nt], 0, 0, 0);
    }
  }
#pragma unroll
  for (int mi = 0; mi < 2; ++mi)
#pragma unroll
    for (int nt = 0; nt < 8; ++nt)
#pragma unroll
      for (int r = 0; r < 4; ++r)
        Kf[(size_t)(m0 + mi * 16 + quad * 4 + r) * DIM + nt * 16 + l15] =
            (_Float16)acc[mi][nt][r];
}

// ---------------- kernel 2: S[b] = F_b @ Kf_b^T, one wave per batch ------------------
// No LDS, no barriers. A = F rows (fp32->fp16 cvt), B = Kf rows (16B fp16 frags).
__global__ __launch_bounds__(256, 4)
void s2_kernel(const float* __restrict__ F,
               const _Float16* __restrict__ Kf,
               _Float16* __restrict__ Sg, int c0) {
  const int t = threadIdx.x;
  const int lane = t & 63, wave = t >> 6;
  const int l15 = lane & 15, quad = lane >> 4;
  const int bl = blockIdx.x * 4 + wave;                     // chunk-local batch
  const float* Fb = F + ((size_t)(c0 + bl) * NFIELD) * DIM;
  const _Float16* Kb = Kf + (size_t)bl * NFIELD * DIM;

  f32x4 acc[4][4];
#pragma unroll
  for (int it = 0; it < 4; ++it)
#pragma unroll
    for (int jt = 0; jt < 4; ++jt) acc[it][jt] = (f32x4){0.f, 0.f, 0.f, 0.f};

#pragma unroll
  for (int kt = 0; kt < 4; ++kt) {
    const int k0 = kt * 32 + quad * 8;
    f16x8 af[4], bf[4];
#pragma unroll
    for (int it = 0; it < 4; ++it) {
      const float* fp = Fb + (it * 16 + l15) * DIM + k0;
      float4 f0 = *(const float4*)fp;
      float4 f1 = *(const float4*)(fp + 4);
      f16x8 a;
      a[0] = (_Float16)f0.x; a[1] = (_Float16)f0.y; a[2] = (_Float16)f0.z; a[3] = (_Float16)f0.w;
      a[4] = (_Float16)f1.x; a[5] = (_Float16)f1.y; a[6] = (_Float16)f1.z; a[7] = (_Float16)f1.w;
      af[it] = a;
      bf[it] = *(const f16x8*)(Kb + (it * 16 + l15) * DIM + k0);
    }
#pragma unroll
    for (int it = 0; it < 4; ++it)
#pragma unroll
      for (int jt = 0; jt < 4; ++jt)
        acc[it][jt] = __builtin_amdgcn_mfma_f32_16x16x32_f16(af[it], bf[jt], acc[it][jt], 0, 0, 0);
  }

  _Float16* Sb = Sg + (size_t)bl * (NFIELD * NFIELD);
#pragma unroll
  for (int it = 0; it < 4; ++it)
#pragma unroll
    for (int jt = 0; jt < 4; ++jt)
#pragma unroll
      for (int r = 0; r < 4; ++r)
        Sb[(it * 16 + quad * 4 + r) * 64 + jt * 16 + l15] = (_Float16)acc[it][jt][r];
}

// ---------------- kernel B: out[b,i,:] = S[b,i,:]@W[i] + F[b,i,:]@Qw^T ----------------
// grid (b-chunks of 128, i in 0..63). Augmented GEMM: [128 x 192] @ [192 x 128].
// A row b: k<64 -> S[b,i,k] ; k>=64 -> F[b,i,k-64]. B row d (LDS): [Wt[i][d][:64] | Qh[d][:128]].
__global__ __launch_bounds__(256, 3)
void out_kernel(const float* __restrict__ F,
                const _Float16* __restrict__ Sg,
                const _Float16* __restrict__ Wt,
                const _Float16* __restrict__ Qh,
                float* __restrict__ Out, int c0) {
  __shared__ _Float16 sBt[128 * 200];  // row stride 200 halves (400B, 16-aligned)
  const int i = blockIdx.y;
  const int t = threadIdx.x;
  const int lane = t & 63, wave = t >> 6;
  const int l15 = lane & 15, quad = lane >> 4;

  const f16x8* wp = (const f16x8*)(Wt + (size_t)i * DIM * NFIELD);
  for (int idx = t; idx < 1024; idx += 256) {      // 128*64 halves / 8
    int d = idx >> 3, jw = idx & 7;
    *(f16x8*)&sBt[d * 200 + jw * 8] = wp[idx];
  }
  const f16x8* qp = (const f16x8*)Qh;
  for (int idx = t; idx < 2048; idx += 256) {      // 128*128 halves / 8
    int d = idx >> 4, ew = idx & 15;
    *(f16x8*)&sBt[d * 200 + 64 + ew * 8] = qp[idx];
  }
  __syncthreads();

  f32x4 acc[2][8];
#pragma unroll
  for (int mi = 0; mi < 2; ++mi)
#pragma unroll
    for (int nt = 0; nt < 8; ++nt) acc[mi][nt] = (f32x4){0.f, 0.f, 0.f, 0.f};

  const int bl0 = blockIdx.x * 128;
#pragma unroll
  for (int kt = 0; kt < 6; ++kt) {
    f16x8 af[2];
#pragma unroll
    for (int mi = 0; mi < 2; ++mi) {
      const int bl = bl0 + (wave * 2 + mi) * 16 + l15;
      if (kt < 2) {
        const int j0 = kt * 32 + quad * 8;
        af[mi] = *(const f16x8*)(Sg + (size_t)bl * 4096 + i * 64 + j0);
      } else {
        const int e0 = (kt - 2) * 32 + quad * 8;
        const float* fp = F + ((size_t)(c0 + bl) * NFIELD + i) * DIM + e0;
        float4 f0 = *(const float4*)fp;
        float4 f1 = *(const float4*)(fp + 4);
        f16x8 a;
        a[0] = (_Float16)f0.x; a[1] = (_Float16)f0.y; a[2] = (_Float16)f0.z; a[3] = (_Float16)f0.w;
        a[4] = (_Float16)f1.x; a[5] = (_Float16)f1.y; a[6] = (_Float16)f1.z; a[7] = (_Float16)f1.w;
        af[mi] = a;
      }
    }
#pragma unroll
    for (int nt = 0; nt < 8; ++nt) {
      f16x8 bf = *(const f16x8*)&sBt[(nt * 16 + l15) * 200 + kt * 32 + quad * 8];
      acc[0][nt] = __builtin_amdgcn_mfma_f32_16x16x32_f16(af[0], bf, acc[0][nt], 0, 0, 0);
      acc[1][nt] = __builtin_amdgcn_mfma_f32_16x16x32_f16(af[1], bf, acc[1][nt], 0, 0, 0);
    }
  }

#pragma unroll
  for (int mi = 0; mi < 2; ++mi) {
    const int blr = bl0 + (wave * 2 + mi) * 16 + quad * 4;
#pragma unroll
    for (int nt = 0; nt < 8; ++nt) {
      const int d = nt * 16 + l15;
#pragma unroll
      for (int r = 0; r < 4; ++r) {
        const size_t gb = (size_t)(c0 + blr + r);
        Out[(gb * NFIELD + i) * DIM + d] = acc[mi][nt][r];
      }
    }
  }
}

extern "C" void kernel_launch(void* const* d_in, const int* in_sizes, int n_in,
                              void* d_out, int out_size, void* d_ws, size_t ws_size,
                              hipStream_t stream) {
  const float* F  = (const float*)d_in[0];
  const float* W  = (const float*)d_in[1];
  const float* Kw = (const float*)d_in[2];
  const float* Qw = (const float*)d_in[3];
  float* Out = (float*)d_out;

  // workspace layout: Wt (1 MB) | Kh (32 KB) | Qh (32 KB) | Kf (CB*16KB) | S (CB*8KB)
  _Float16* Wt = (_Float16*)d_ws;
  _Float16* Kh = Wt + (size_t)NFIELD * DIM * NFIELD;
  _Float16* Qh = Kh + DIM * DIM;
  _Float16* Kf = Qh + DIM * DIM;
  const size_t fixed_bytes = ((size_t)NFIELD * DIM * NFIELD + 2 * DIM * DIM) * sizeof(_Float16);
  const size_t per_batch = ((size_t)NFIELD * DIM + NFIELD * NFIELD) * sizeof(_Float16);
  size_t avail = (ws_size > fixed_bytes) ? (ws_size - fixed_bytes) : 0;
  int CB = BTOT;
  while (CB > 128 && (size_t)CB * per_batch > avail) CB >>= 1;
  _Float16* Sg = Kf + (size_t)CB * NFIELD * DIM;

  prep_kernel<<<dim3(NFIELD + 2), 256, 0, stream>>>(W, Kw, Qw, Wt, Kh, Qh);
  for (int c0 = 0; c0 < BTOT; c0 += CB) {
    kf_kernel<<<dim3(CB / 2), 256, 0, stream>>>(F, Kh, Kf, c0);
    s2_kernel<<<dim3(CB / 4), 256, 0, stream>>>(F, Kf, Sg, c0);
    out_kernel<<<dim3(CB / 128, NFIELD), 256, 0, stream>>>(F, Sg, Wt, Qh, Out, c0);
  }
}